// Round 15
// baseline (143.154 us; speedup 1.0000x reference)
//
#include <hip/hip_runtime.h>
#include <hip/hip_bf16.h>
#include <math.h>

#define BB 64
#define NN 1025
#define DD 768
#define HH 128
#define KK 256
#define TOK (BB*NN)          // 65600
#define OUT_XRED 0
#define OUT_IDX  (BB*(KK+1)*DD)            // 12,632,064
#define OUT_SC   (OUT_IDX + BB*(KK+1))     // + 16,448

typedef float    f32x4 __attribute__((ext_vector_type(4)));
typedef __fp16   h16x2 __attribute__((ext_vector_type(2)));
typedef _Float16 f16x8 __attribute__((ext_vector_type(8)));
#define NSTEP (DD/32)        // 24 MFMA k-steps

union U4F { uint4 u; f16x8 h; };
union H2U { h16x2 h; unsigned int u; };

// ---- K0: W1w = lnw ∘ W1 -> f16, MFMA-frag-transposed layout --------
__global__ __launch_bounds__(256) void k_cvtw(const float* __restrict__ w1,
                                              const float* __restrict__ lnw,
                                              unsigned short* __restrict__ wt)
{
    int i = blockIdx.x*256 + threadIdx.x;    // 98304 exact
    int k = i >> 7, n = i & 127;
    union { _Float16 h; unsigned short s; } c;
    c.h = (_Float16)(w1[i] * lnw[k]);
    int s = k >> 5, g = (k >> 3) & 3, j = k & 7;
    wt[((s*4 + g)*HH + n)*8 + j] = c.s;
}

// ---- K0b: c1[n] = lnb@W1 + b1, c2[n] = lnw@W1 ----------------------
__global__ __launch_bounds__(1024) void k_cvec(const float* __restrict__ w1,
                                               const float* __restrict__ lnw,
                                               const float* __restrict__ lnb,
                                               const float* __restrict__ b1,
                                               float* __restrict__ cvec)
{
    __shared__ float red[2][8][128];
    const int n = threadIdx.x & 127;
    const int r = threadIdx.x >> 7;          // 0..7
    float s1 = 0.f, s2 = 0.f;
    #pragma unroll 8
    for (int j = 0; j < 96; ++j) {
        int k = r + j*8;
        float wv = w1[k*HH + n];
        s1 = fmaf(lnb[k], wv, s1);
        s2 = fmaf(lnw[k], wv, s2);
    }
    red[0][r][n] = s1;
    red[1][r][n] = s2;
    __syncthreads();
    if (r == 0) {
        float t1 = 0.f, t2 = 0.f;
        #pragma unroll
        for (int q = 0; q < 8; ++q) { t1 += red[0][q][n]; t2 += red[1][q][n]; }
        cvec[n]     = t1 + b1[n];
        cvec[128+n] = t2;
    }
}

// ---- K_pack: streaming. Read x once, f32 stats, pkrtz pack, LDS
// bounce transpose, write xh in MFMA-fragment order (coalesced) + mr.
// xh chunk layout: xh[tile*1536 + c*16 + t16] (uint4) holds token
// (tile*16+t16), elements [c*8, c*8+8) as f16.
__global__ __launch_bounds__(256) void k_pack(const float* __restrict__ x,
                                              float2* __restrict__ mr,
                                              uint4* __restrict__ xh)
{
    __shared__ uint4 planes[16*96];     // 24 KB
    const int tid = threadIdx.x;
    const int row = tid >> 4, l16 = tid & 15;
    const int rsz = row & 7;
    const int tok0 = blockIdx.x * 16;   // grid 4100 exact

    const float4* srow4 = reinterpret_cast<const float4*>(x + (size_t)(tok0 + row) * DD);
    float s_ = 0.f, ss = 0.f;
    #pragma unroll
    for (int j = 0; j < 6; ++j) {
        float4 a = srow4[l16*2 + j*32];
        float4 b = srow4[l16*2 + j*32 + 1];
        s_ += ((a.x + a.y) + (a.z + a.w)) + ((b.x + b.y) + (b.z + b.w));
        ss += a.x*a.x + a.y*a.y + a.z*a.z + a.w*a.w
            + b.x*b.x + b.y*b.y + b.z*b.z + b.w*b.w;
        H2U h01, h23, h45, h67;
        h01.h = __builtin_amdgcn_cvt_pkrtz(a.x, a.y);
        h23.h = __builtin_amdgcn_cvt_pkrtz(a.z, a.w);
        h45.h = __builtin_amdgcn_cvt_pkrtz(b.x, b.y);
        h67.h = __builtin_amdgcn_cvt_pkrtz(b.z, b.w);
        planes[row*96 + ((l16 + j*16) ^ rsz)] = make_uint4(h01.u, h23.u, h45.u, h67.u);
    }
    #pragma unroll
    for (int m = 8; m; m >>= 1) { s_ += __shfl_xor(s_, m, 64); ss += __shfl_xor(ss, m, 64); }
    const float mu = s_ * (1.0f/768.0f);
    const float rs = 1.0f / sqrtf(ss * (1.0f/768.0f) - mu*mu + 1e-5f);
    if (l16 == 0) mr[tok0 + row] = make_float2(mu, rs);
    __syncthreads();

    // reader role: thread (cw, t16p) emits chunks c = cw + jj*16 of token t16p
    const int cw = tid >> 4, t16p = tid & 15, sz2 = t16p & 7;
    uint4* dst = xh + (size_t)blockIdx.x * 1536;
    #pragma unroll
    for (int jj = 0; jj < 6; ++jj) {
        const int c = cw + jj*16;
        dst[c*16 + t16p] = planes[t16p*96 + (c ^ sz2)];
    }
}

// ---- K_score: ZERO LDS, zero barriers. A from xh (coalesced 1KB/step,
// L1-shared across the 4 waves), B depth-1 prefetch, folded-LN epilogue.
__global__ __launch_bounds__(256) void k_score(const uint4* __restrict__ xh,
    const unsigned short* __restrict__ wt,
    const float* __restrict__ cvec,
    const float* __restrict__ w2, const float* __restrict__ b2,
    const float2* __restrict__ mr,
    float* __restrict__ scores_out)
{
    const int tid  = threadIdx.x;
    const int wave = tid >> 6, lane = tid & 63;
    const int g    = lane >> 4, t16 = lane & 15;
    const int tok0 = blockIdx.x * 16;    // grid 4100 exact
    const int colbase = wave * 32;

    const uint4* ap = xh + (size_t)blockIdx.x * 1536 + g*16 + t16;
    const unsigned short* wtp = wt + ((size_t)g*HH + colbase + t16)*8;

    f32x4 acc0 = {0,0,0,0}, acc1 = {0,0,0,0};
    U4F nA; nA.u = ap[0];
    f16x8 nB0 = *reinterpret_cast<const f16x8*>(wtp);
    f16x8 nB1 = *reinterpret_cast<const f16x8*>(wtp + 128);

    #pragma unroll
    for (int s = 0; s < NSTEP; ++s) {
        U4F A = nA;
        f16x8 B0 = nB0, B1 = nB1;
        if (s + 1 < NSTEP) {
            nA.u = ap[(s+1)*64];
            nB0 = *reinterpret_cast<const f16x8*>(wtp + (size_t)(s+1)*4096);
            nB1 = *reinterpret_cast<const f16x8*>(wtp + (size_t)(s+1)*4096 + 128);
        }
        acc0 = __builtin_amdgcn_mfma_f32_16x16x32_f16(A.h, B0, acc0, 0, 0, 0);
        acc1 = __builtin_amdgcn_mfma_f32_16x16x32_f16(A.h, B1, acc1, 0, 0, 0);
    }

    // epilogue: folded LN + exact gelu + w2-dot + 16-lane reduce
    const int c0 = colbase + t16, c1i = colbase + 16 + t16;
    const float c1A = cvec[c0],  c2A = cvec[128 + c0];
    const float c1B = cvec[c1i], c2B = cvec[128 + c1i];
    const float w2A = w2[c0],    w2B = w2[c1i];
    const float is2 = 0.70710678f;

    __shared__ float part[4][16];
    float psum[4];
    #pragma unroll
    for (int r = 0; r < 4; ++r) {
        const float2 m2 = mr[tok0 + g*4 + r];
        const float mur = m2.x, rsr = m2.y;
        float v0 = rsr*acc0[r] + c1A - mur*rsr*c2A;
        float v1 = rsr*acc1[r] + c1B - mur*rsr*c2B;
        float g0 = 0.5f * v0 * (1.0f + erff(v0 * is2));
        float g1 = 0.5f * v1 * (1.0f + erff(v1 * is2));
        float p = g0 * w2A + g1 * w2B;
        #pragma unroll
        for (int m = 8; m; m >>= 1) p += __shfl_xor(p, m, 64);
        psum[r] = p;
    }
    if (t16 == 0) {
        #pragma unroll
        for (int r = 0; r < 4; ++r) part[wave][g*4 + r] = psum[r];
    }
    __syncthreads();
    if (tid < 16) {
        float s = part[0][tid] + part[1][tid] + part[2][tid] + part[3][tid] + b2[0];
        int tok = tok0 + tid;
        scores_out[tok] = ((tok % NN) == 0) ? 1.0e9f : s;
    }
}

// ---- K3: per-batch bitonic top-k (full 1024 sort, f32) -------------
__global__ __launch_bounds__(1024) void k_topk(const float* __restrict__ scores,
                                               float* __restrict__ idx_out)
{
    __shared__ float sk_[1024];
    __shared__ int   si[1024];
    const int tid = threadIdx.x;
    const int b   = blockIdx.x;
    sk_[tid] = scores[b*NN + 1 + tid];
    si[tid] = tid + 1;
    __syncthreads();
    for (int k = 2; k <= 1024; k <<= 1) {
        for (int j = k >> 1; j > 0; j >>= 1) {
            int ixj = tid ^ j;
            if (ixj > tid) {
                float sa = sk_[tid]; int ia = si[tid];
                float sb = sk_[ixj]; int ib = si[ixj];
                bool beforeB = (sb > sa) || (sb == sa && ib < ia);
                bool dirAsc  = ((tid & k) == 0);
                if (beforeB == dirAsc) {
                    sk_[tid] = sb; si[tid] = ib;
                    sk_[ixj] = sa; si[ixj] = ia;
                }
            }
            __syncthreads();
        }
    }
    if (tid == 0)  idx_out[b*(KK+1)] = 0.0f;
    if (tid < KK)  idx_out[b*(KK+1) + 1 + tid] = (float)si[tid];
}

// ---- K4: gather selected tokens (wide grid, streaming) -------------
__global__ __launch_bounds__(192) void k_gather(const float* __restrict__ x,
                                                const float* __restrict__ idx_out,
                                                float* __restrict__ xred)
{
    const int r = blockIdx.x;               // 0 .. 64*257-1
    const int b = r / (KK+1);
    const int idx = (int)(idx_out[r] + 0.5f);
    const float4* src = reinterpret_cast<const float4*>(x + ((size_t)b*NN + idx) * DD);
    float4* dst = reinterpret_cast<float4*>(xred + (size_t)r * DD);
    dst[threadIdx.x] = src[threadIdx.x];
}

extern "C" void kernel_launch(void* const* d_in, const int* in_sizes, int n_in,
                              void* d_out, int out_size, void* d_ws, size_t ws_size,
                              hipStream_t stream)
{
    const float* x   = (const float*)d_in[0];
    const float* lnw = (const float*)d_in[1];
    const float* lnb = (const float*)d_in[2];
    const float* w1  = (const float*)d_in[3];
    const float* b1  = (const float*)d_in[4];
    const float* w2  = (const float*)d_in[5];
    const float* b2  = (const float*)d_in[6];

    float* out   = (float*)d_out;
    float* xred  = out + OUT_XRED;
    float* idxf  = out + OUT_IDX;
    float* scout = out + OUT_SC;

    char* wsb = (char*)d_ws;
    unsigned short* wt = (unsigned short*)wsb;            // 196,608 B
    float* cvec = (float*)(wsb + 196608);                 //   1,024 B
    float2* mr  = (float2*)(wsb + 197632);                // 524,800 B
    uint4* xh   = (uint4*)(wsb + 722432);                 // 100,761,600 B

    k_cvtw <<<DD*HH/256, 256, 0, stream>>>(w1, lnw, wt);
    k_cvec <<<1, 1024, 0, stream>>>(w1, lnw, lnb, b1, cvec);
    k_pack <<<TOK/16, 256, 0, stream>>>(x, mr, xh);
    k_score<<<TOK/16, 256, 0, stream>>>(xh, wt, cvec, w2, b2, mr, scout);
    k_topk <<<BB, 1024, 0, stream>>>(scout, idxf);
    k_gather<<<BB*(KK+1), 192, 0, stream>>>(x, idxf, xred);
}

// Round 16
// 96.519 us; speedup vs baseline: 1.4832x; 1.4832x over previous
//
#include <hip/hip_runtime.h>
#include <hip/hip_bf16.h>
#include <math.h>

#define BB 64
#define NN 1025
#define DD 768
#define HH 128
#define KK 256
#define TOK (BB*NN)          // 65600
#define OUT_XRED 0
#define OUT_IDX  (BB*(KK+1)*DD)            // 12,632,064
#define OUT_SC   (OUT_IDX + BB*(KK+1))     // + 16,448

typedef float    f32x4 __attribute__((ext_vector_type(4)));
typedef __fp16   h16x2 __attribute__((ext_vector_type(2)));
typedef _Float16 f16x8 __attribute__((ext_vector_type(8)));
#define NSTEP (DD/32)        // 24 MFMA k-steps

union U4F { uint4 u; f16x8 h; };
union H2U { h16x2 h; unsigned int u; };

// ---- K0: W1w = lnw ∘ W1 -> f16, MFMA-frag-transposed layout --------
__global__ __launch_bounds__(256) void k_cvtw(const float* __restrict__ w1,
                                              const float* __restrict__ lnw,
                                              unsigned short* __restrict__ wt)
{
    int i = blockIdx.x*256 + threadIdx.x;    // 98304 exact
    int k = i >> 7, n = i & 127;
    union { _Float16 h; unsigned short s; } c;
    c.h = (_Float16)(w1[i] * lnw[k]);
    int s = k >> 5, g = (k >> 3) & 3, j = k & 7;
    wt[((s*4 + g)*HH + n)*8 + j] = c.s;
}

// ---- K0b: c1[n] = lnb@W1 + b1, c2[n] = lnw@W1 ----------------------
__global__ __launch_bounds__(1024) void k_cvec(const float* __restrict__ w1,
                                               const float* __restrict__ lnw,
                                               const float* __restrict__ lnb,
                                               const float* __restrict__ b1,
                                               float* __restrict__ cvec)
{
    __shared__ float red[2][8][128];
    const int n = threadIdx.x & 127;
    const int r = threadIdx.x >> 7;          // 0..7
    float s1 = 0.f, s2 = 0.f;
    #pragma unroll 8
    for (int j = 0; j < 96; ++j) {
        int k = r + j*8;
        float wv = w1[k*HH + n];
        s1 = fmaf(lnb[k], wv, s1);
        s2 = fmaf(lnw[k], wv, s2);
    }
    red[0][r][n] = s1;
    red[1][r][n] = s2;
    __syncthreads();
    if (r == 0) {
        float t1 = 0.f, t2 = 0.f;
        #pragma unroll
        for (int q = 0; q < 8; ++q) { t1 += red[0][q][n]; t2 += red[1][q][n]; }
        cvec[n]     = t1 + b1[n];
        cvec[128+n] = t2;
    }
}

// ---- K_fused: 16 tokens/block, 4 waves, 24KB LDS.
// __launch_bounds__(256, 8): force <=64 VGPR so each wave fits the
// 64-reg allocation slot -> 8 waves/SIMD possible; LDS then caps at
// 6 blocks/CU = 24 waves (was 16 at VGPR=72). Latency-bound kernel:
// +50% TLP is the lever.
__global__ __launch_bounds__(256, 8) void k_fused(const float* __restrict__ x,
    const unsigned short* __restrict__ wt,
    const float* __restrict__ cvec,
    const float* __restrict__ w2, const float* __restrict__ b2,
    float* __restrict__ scores_out)
{
    __shared__ uint4 planes[16*96];     // 24 KB, raw-x f16 plane
    __shared__ float mus[16], rss[16];
    __shared__ float part[4][16];

    const int tid  = threadIdx.x;
    const int wave = tid >> 6, lane = tid & 63;
    const int g    = lane >> 4, t16 = lane & 15;
    const int t7   = t16 & 7;
    const int tok0 = blockIdx.x * 16;     // grid 4100 exact
    const int colbase = wave * 32;
    const int row = tid >> 4, l16 = tid & 15;

    // ---- pass A: load row, f32 stats, pack raw x -> plane
    const float4* srow4 = reinterpret_cast<const float4*>(x + (size_t)(tok0 + row) * DD);
    const int rsz = row & 7;
    float s_ = 0.f, ss = 0.f;
    #pragma unroll
    for (int j = 0; j < 6; ++j) {
        float4 a = srow4[l16*2 + j*32];
        float4 b = srow4[l16*2 + j*32 + 1];
        s_ += ((a.x + a.y) + (a.z + a.w)) + ((b.x + b.y) + (b.z + b.w));
        ss += a.x*a.x + a.y*a.y + a.z*a.z + a.w*a.w
            + b.x*b.x + b.y*b.y + b.z*b.z + b.w*b.w;
        H2U h01, h23, h45, h67;
        h01.h = __builtin_amdgcn_cvt_pkrtz(a.x, a.y);
        h23.h = __builtin_amdgcn_cvt_pkrtz(a.z, a.w);
        h45.h = __builtin_amdgcn_cvt_pkrtz(b.x, b.y);
        h67.h = __builtin_amdgcn_cvt_pkrtz(b.z, b.w);
        planes[row*96 + ((l16 + j*16) ^ rsz)] = make_uint4(h01.u, h23.u, h45.u, h67.u);
    }
    #pragma unroll
    for (int m = 8; m; m >>= 1) { s_ += __shfl_xor(s_, m, 64); ss += __shfl_xor(ss, m, 64); }
    const float mu = s_ * (1.0f/768.0f);
    const float rs = 1.0f / sqrtf(ss * (1.0f/768.0f) - mu*mu + 1e-5f);
    if (l16 == 0) { mus[row] = mu; rss[row] = rs; }

    // ---- prefetch step-0 B fragments (stay in flight across barrier)
    const unsigned short* wtp = wt + ((size_t)g*HH + colbase + t16)*8;
    f16x8 nB0 = *reinterpret_cast<const f16x8*>(wtp);
    f16x8 nB1 = *reinterpret_cast<const f16x8*>(wtp + 128);

    // lgkmcnt-only barrier: LDS writes visible, VMEM (B) not drained
    asm volatile("s_waitcnt lgkmcnt(0)" ::: "memory");
    __builtin_amdgcn_s_barrier();

    // ---- phase C: fully-unrolled MFMA loop with rotating B prefetch
    f32x4 acc0 = {0,0,0,0}, acc1 = {0,0,0,0};
    #pragma unroll
    for (int s = 0; s < NSTEP; ++s) {
        f16x8 B0 = nB0, B1 = nB1;
        if (s + 1 < NSTEP) {
            nB0 = *reinterpret_cast<const f16x8*>(wtp + (size_t)(s+1)*4096);
            nB1 = *reinterpret_cast<const f16x8*>(wtp + (size_t)(s+1)*4096 + 128);
        }
        U4F Ah;
        Ah.u = planes[((s*4 + g) ^ t7) + t16*96];
        acc0 = __builtin_amdgcn_mfma_f32_16x16x32_f16(Ah.h, B0, acc0, 0, 0, 0);
        acc1 = __builtin_amdgcn_mfma_f32_16x16x32_f16(Ah.h, B1, acc1, 0, 0, 0);
    }

    // ---- epilogue: folded LN + exact gelu (f32) + w2-dot + reduce
    const int c0 = colbase + t16, c1i = colbase + 16 + t16;
    const float c1A = cvec[c0],      c2A = cvec[128 + c0];
    const float c1B = cvec[c1i],     c2B = cvec[128 + c1i];
    const float w2A = w2[c0],        w2B = w2[c1i];
    const float is2 = 0.70710678f;

    float psum[4];
    #pragma unroll
    for (int r = 0; r < 4; ++r) {
        const float mur = mus[g*4 + r], rsr = rss[g*4 + r];
        float v0 = rsr*acc0[r] + c1A - mur*rsr*c2A;
        float v1 = rsr*acc1[r] + c1B - mur*rsr*c2B;
        float g0 = 0.5f * v0 * (1.0f + erff(v0 * is2));
        float g1 = 0.5f * v1 * (1.0f + erff(v1 * is2));
        float p = g0 * w2A + g1 * w2B;
        #pragma unroll
        for (int m = 8; m; m >>= 1) p += __shfl_xor(p, m, 64);
        psum[r] = p;
    }
    if (t16 == 0) {
        #pragma unroll
        for (int r = 0; r < 4; ++r) part[wave][g*4 + r] = psum[r];
    }
    __syncthreads();
    if (tid < 16) {
        float s = part[0][tid] + part[1][tid] + part[2][tid] + part[3][tid] + b2[0];
        int tok = tok0 + tid;
        scores_out[tok] = ((tok % NN) == 0) ? 1.0e9f : s;
    }
}

// ---- K3: per-batch bitonic top-k (full 1024 sort, f32) -------------
__global__ __launch_bounds__(1024) void k_topk(const float* __restrict__ scores,
                                               float* __restrict__ idx_out)
{
    __shared__ float sk_[1024];
    __shared__ int   si[1024];
    const int tid = threadIdx.x;
    const int b   = blockIdx.x;
    sk_[tid] = scores[b*NN + 1 + tid];
    si[tid] = tid + 1;
    __syncthreads();
    for (int k = 2; k <= 1024; k <<= 1) {
        for (int j = k >> 1; j > 0; j >>= 1) {
            int ixj = tid ^ j;
            if (ixj > tid) {
                float sa = sk_[tid]; int ia = si[tid];
                float sb = sk_[ixj]; int ib = si[ixj];
                bool beforeB = (sb > sa) || (sb == sa && ib < ia);
                bool dirAsc  = ((tid & k) == 0);
                if (beforeB == dirAsc) {
                    sk_[tid] = sb; si[tid] = ib;
                    sk_[ixj] = sa; si[ixj] = ia;
                }
            }
            __syncthreads();
        }
    }
    if (tid == 0)  idx_out[b*(KK+1)] = 0.0f;
    if (tid < KK)  idx_out[b*(KK+1) + 1 + tid] = (float)si[tid];
}

// ---- K4: gather selected tokens (wide grid, streaming) -------------
__global__ __launch_bounds__(192) void k_gather(const float* __restrict__ x,
                                                const float* __restrict__ idx_out,
                                                float* __restrict__ xred)
{
    const int r = blockIdx.x;               // 0 .. 64*257-1
    const int b = r / (KK+1);
    const int idx = (int)(idx_out[r] + 0.5f);
    const float4* src = reinterpret_cast<const float4*>(x + ((size_t)b*NN + idx) * DD);
    float4* dst = reinterpret_cast<float4*>(xred + (size_t)r * DD);
    dst[threadIdx.x] = src[threadIdx.x];
}

extern "C" void kernel_launch(void* const* d_in, const int* in_sizes, int n_in,
                              void* d_out, int out_size, void* d_ws, size_t ws_size,
                              hipStream_t stream)
{
    const float* x   = (const float*)d_in[0];
    const float* lnw = (const float*)d_in[1];
    const float* lnb = (const float*)d_in[2];
    const float* w1  = (const float*)d_in[3];
    const float* b1  = (const float*)d_in[4];
    const float* w2  = (const float*)d_in[5];
    const float* b2  = (const float*)d_in[6];

    float* out   = (float*)d_out;
    float* xred  = out + OUT_XRED;
    float* idxf  = out + OUT_IDX;
    float* scout = out + OUT_SC;

    unsigned short* wt = (unsigned short*)d_ws;           // 196,608 B
    float* cvec = (float*)((char*)d_ws + 196608);         // 1,024 B

    k_cvtw <<<DD*HH/256, 256, 0, stream>>>(w1, lnw, wt);
    k_cvec <<<1, 1024, 0, stream>>>(w1, lnw, lnb, b1, cvec);
    k_fused<<<TOK/16, 256, 0, stream>>>(x, wt, cvec, w2, b2, scout);
    k_topk <<<BB, 1024, 0, stream>>>(scout, idxf);
    k_gather<<<BB*(KK+1), 192, 0, stream>>>(x, idxf, xred);
}